// Round 17
// baseline (116.690 us; speedup 1.0000x reference)
//
#include <hip/hip_runtime.h>
#include <hip/hip_bf16.h>

#define QMAX 255.0f

typedef __attribute__((ext_vector_type(8))) short short8;
typedef __attribute__((ext_vector_type(4))) float f32x4;

// ws float offsets
#define OFF_BF1   16       // ushort[4096]
#define OFF_BF2   2064     // ushort[8192]
#define OFF_BF3   6160     // ushort[53248]
#define OFF_BF4   32784    // ushort[12288]
#define OFF_BF5   38928    // ushort[1536]
#define OFF_H1    40960    // padded f32 [4096][6][14][16]
#define OFF_H2    5545984  // f32 [4096][400]  (28.7 MB high water)
#define OFF_H3    40960    // reuses dead h1 region: f32 [4096][120]
#define OFF_H4    532480   // f32 [4096][84]

#define IMG1 3080   // shorts/img conv1 LDS (1540 dw)
#define IMG2 1352   // shorts/img conv2 LDS (676 dw)

__device__ __forceinline__ float get_scale(const unsigned* slots, int i) {
    float amax = __uint_as_float(slots[i]);
    float s = amax / QMAX;
    if (!(s > 0.0f)) s = 1.0f;
    return s;
}
__device__ __forceinline__ unsigned f2bf(float f) { return __float_as_uint(f) >> 16; } // exact for our ints

// signed atomicMax on float bits: valid for non-negative floats; 0xAA poison is
// negative as int -> no slot zeroing needed, and replays are idempotent.
__device__ __forceinline__ void amax_slot(unsigned* p, float v) {
    atomicMax((int*)p, (int)__float_as_uint(v));
}

__device__ __forceinline__ float block_maxN(float v, float* red, int nw) {
    #pragma unroll
    for (int off = 32; off > 0; off >>= 1) v = fmaxf(v, __shfl_xor(v, off));
    if ((threadIdx.x & 63) == 0) red[threadIdx.x >> 6] = v;
    __syncthreads();
    float m = red[0];
    for (int i = 1; i < nw; i++) m = fmaxf(m, red[i]);
    return m;
}

// ---------------- absmax: x (blocks 0..2047) + all 5 weights (parallel w3/w4 scans) ----------------
__global__ __launch_bounds__(256) void k_absmax_all(
    const float4* __restrict__ x4,
    const float* __restrict__ w1, const float* __restrict__ w2,
    const float* __restrict__ w3, const float* __restrict__ w4,
    const float* __restrict__ w5, unsigned* __restrict__ slots)
{
    __shared__ float red[4];
    int b = blockIdx.x, tid = threadIdx.x;
    float m = 0.0f;
    int slot = -1;
    if (b < 2048) {
        slot = 0;
        for (int i = b * 256 + tid; i < 3145728; i += 2048 * 256) {
            float4 v = x4[i];
            m = fmaxf(m, fmaxf(fmaxf(fabsf(v.x), fabsf(v.y)), fmaxf(fabsf(v.z), fabsf(v.w))));
        }
    } else {
        int b2 = b - 2048;
        const float* w = nullptr; int n = 0, start = 0, stride = 256;
        if (b2 < 48)      { w = w3; n = 48000; start = b2 * 256;        stride = 48 * 256; slot = 7; }
        else if (b2 < 58) { w = w4; n = 10080; start = (b2 - 48) * 256; stride = 10 * 256; slot = 8; }
        else if (b2 == 58){ w = w2; n = 2400;  slot = 6; }
        else if (b2 == 59){ w = w1; n = 450;   slot = 5; }
        else if (b2 == 60){ w = w5; n = 840;   slot = 9; }
        if (slot >= 0)
            for (int i = start + tid; i < n; i += stride) m = fmaxf(m, fabsf(w[i]));
    }
    m = block_maxN(m, red, 4);
    if (tid == 0 && slot >= 0) amax_slot(&slots[slot], m);
}

// ---------------- build MFMA B-fragments ----------------
__global__ __launch_bounds__(256) void k_bfrag(
    const float* __restrict__ w1, const float* __restrict__ w2,
    const float* __restrict__ w3, const float* __restrict__ w4,
    const float* __restrict__ w5, const unsigned* __restrict__ slots,
    unsigned short* __restrict__ bf1, unsigned short* __restrict__ bf2,
    unsigned short* __restrict__ bf3, unsigned short* __restrict__ bf4,
    unsigned short* __restrict__ bf5)
{
    int idx = blockIdx.x * 256 + threadIdx.x;
    if (idx < 4096) {                     // conv1: [H2][S4][64][8], n=o*4+dx (o<3,dx<4)
        int f = idx, e = f & 7, l = (f >> 3) & 63, s = (f >> 9) & 3, H = f >> 11;
        int n = l & 15, g = l >> 4, C = 4 * s + g;
        float v = 0.f;
        if (n < 12 && C < 15) {
            int o = n >> 2, dx = n & 3, kx = e - dx;
            if (kx >= 0 && kx <= 4) {
                int c = C / 5, ky = C % 5, oc = 3 * H + o;
                v = rintf(w1[((oc * 3 + c) * 5 + ky) * 5 + kx] / get_scale(slots, 5));
            }
        }
        bf1[f] = (unsigned short)f2bf(v);
    } else if (idx < 12288) {             // conv2: [H2][S8][64][8], n=o*2+dx (o<8,dx<2)
        int f = idx - 4096, e = f & 7, l = (f >> 3) & 63, s = (f >> 9) & 7, H = f >> 12;
        int n = l & 15, g = l >> 4, C = 4 * s + g;
        float v = 0.f;
        if (C < 30) {
            int o = n >> 1, dx = n & 1, kx = e - dx;
            if (kx >= 0 && kx <= 4) {
                int c = C / 5, ky = C % 5, oc = 8 * H + o;
                v = rintf(w2[((oc * 6 + c) * 5 + ky) * 5 + kx] / get_scale(slots, 6));
            }
        }
        bf2[f] = (unsigned short)f2bf(v);
    } else if (idx < 65536) {             // conv3: [Nt8][S13][64][8]
        int f = idx - 12288, e = f & 7, l = (f >> 3) & 63, r = f >> 9;
        int s = r % 13, Nt = r / 13;
        int oc = Nt * 16 + (l & 15), k = 32 * s + 8 * (l >> 4) + e;
        float v = 0.f;
        if (oc < 120 && k < 400) v = rintf(w3[oc * 400 + k] / get_scale(slots, 7));
        bf3[f] = (unsigned short)f2bf(v);
    } else if (idx < 77824) {             // fc4: [Nt6][S4][64][8]
        int f = idx - 65536, e = f & 7, l = (f >> 3) & 63, r = f >> 9;
        int s = r & 3, Nt = r >> 2;
        int oc = Nt * 16 + (l & 15), k = 32 * s + 8 * (l >> 4) + e;
        float v = 0.f;
        if (oc < 84 && k < 120) v = rintf(w4[oc * 120 + k] / get_scale(slots, 8));
        bf4[f] = (unsigned short)f2bf(v);
    } else if (idx < 79360) {             // fc5: [S3][64][8]
        int f = idx - 77824, e = f & 7, l = (f >> 3) & 63, s = f >> 9;
        int oc = l & 15, k = 32 * s + 8 * (l >> 4) + e;
        float v = 0.f;
        if (oc < 10 && k < 84) v = rintf(w5[oc * 84 + k] / get_scale(slots, 9));
        bf5[f] = (unsigned short)f2bf(v);
    }
}

// ---------------- conv1 MFMA: [B,3,32,32] -> padded h1 [B,6,14,16], 6 img/block, grid 683 ----------------
// A-row il = 2*img + half; half selects py in {0..6} / {7..13}; wave = uu = py-in-half;
// pb = inner register loop -> full-row float4 stores. Rows for img>=nimg masked at store.
__global__ __launch_bounds__(512) void k_conv1(
    const float* __restrict__ x, const unsigned short* __restrict__ bf1,
    const unsigned* __restrict__ slots, unsigned* __restrict__ slot_out,
    float* __restrict__ h1)
{
    __shared__ unsigned short xs[6 * IMG1];
    __shared__ float red[8];
    int b0 = blockIdx.x * 6, tid = threadIdx.x;
    int nimg = min(6, 4096 - b0);
    int lane = tid & 63, wid = tid >> 6;
    int il = lane & 15, g = lane >> 4;
    short8 Bf[2][4];
    #pragma unroll
    for (int H = 0; H < 2; H++)
        #pragma unroll
        for (int s = 0; s < 4; s++)
            Bf[H][s] = *(const short8*)(bf1 + ((H * 4 + s) * 64 + lane) * 8);
    float sx = get_scale(slots, 0);
    for (int img = 0; img < nimg; img++) {
        const float* xb = x + (long)(b0 + img) * 3072;
        for (int i = tid; i < 768; i += 512) {           // quad-index float4 staging
            int c = i >> 8, rem = i & 255, yy = rem >> 3, c4 = (rem & 7) << 2;
            float4 v = *(const float4*)(xb + c * 1024 + yy * 32 + c4);
            uint2 pk;
            pk.x = f2bf(rintf(v.x / sx)) | (f2bf(rintf(v.y / sx)) << 16);
            pk.y = f2bf(rintf(v.z / sx)) | (f2bf(rintf(v.w / sx)) << 16);
            *(uint2*)&xs[img * IMG1 + c * 1024 + yy * 32 + c4] = pk;
        }
    }
    __syncthreads();
    float mscale = sx * get_scale(slots, 5);

    int im = il >> 1; if (im > 5) im = 5;                // clamp: rows 12-15 read img 5 (unused)
    int abase[4];
    #pragma unroll
    for (int s = 0; s < 4; s++) {
        int C = 4 * s + g; if (C > 14) C = 14;
        abase[s] = im * IMG1 + (C / 5) * 1024 + (C % 5) * 32 + (il & 1) * 448;
    }
    int o = il >> 2;
    bool doSt = ((il & 3) == 0) && (il < 12);
    float vmax = 0.f;
    if (wid < 7) {
        int uu = wid;                 // py within half (0..6)
        int ybase = uu * 64;          // (2*uu)*32 shorts
        f32x4 v0[2][2], v1[2][2];     // [H][pb&1] pooled px-pairs
        #pragma unroll
        for (int pb = 0; pb < 7; pb++) {
            f32x4 acc[2][2];
            #pragma unroll
            for (int H = 0; H < 2; H++)
                #pragma unroll
                for (int yo = 0; yo < 2; yo++) acc[H][yo] = (f32x4){0.f, 0.f, 0.f, 0.f};
            #pragma unroll
            for (int yo = 0; yo < 2; yo++) {
                #pragma unroll
                for (int s = 0; s < 4; s++) {
                    int addr = abase[s] + ybase + yo * 32 + 4 * pb;
                    union { unsigned long long u[2]; short8 v; } tA;
                    tA.u[0] = *(const unsigned long long*)(xs + addr);
                    tA.u[1] = *(const unsigned long long*)(xs + addr + 4);
                    acc[0][yo] = __builtin_amdgcn_mfma_f32_16x16x32_bf16(tA.v, Bf[0][s], acc[0][yo], 0, 0, 0);
                    acc[1][yo] = __builtin_amdgcn_mfma_f32_16x16x32_bf16(tA.v, Bf[1][s], acc[1][yo], 0, 0, 0);
                }
            }
            #pragma unroll
            for (int H = 0; H < 2; H++) {
                #pragma unroll
                for (int r = 0; r < 4; r++) {
                    float ym = fmaxf(acc[H][0][r], acc[H][1][r]);     // pool y-pair
                    float p  = fmaxf(ym, __shfl_xor(ym, 1));          // pool dx-pair
                    v0[H][pb & 1][r] = p;
                    v1[H][pb & 1][r] = __shfl_xor(p, 2);              // partner px
                }
            }
            if ((pb & 1) || pb == 6) {                                // flush 2-pb batch
                int pxb = (pb == 6) ? 12 : 2 * (pb - 1);
                bool last = (pb == 6);
                if (doSt) {
                    #pragma unroll
                    for (int H = 0; H < 2; H++)
                        #pragma unroll
                        for (int r = 0; r < 4; r++) {
                            int imgr = 2 * g + (r >> 1);
                            if (imgr < nimg) {
                                int pyr = 7 * (r & 1) + uu;
                                int oc = 3 * H + o;
                                float a0 = fmaxf(v0[H][0][r] * mscale, 0.f);
                                float a1 = fmaxf(v1[H][0][r] * mscale, 0.f);
                                float a2 = last ? 0.f : fmaxf(v0[H][1][r] * mscale, 0.f);
                                float a3 = last ? 0.f : fmaxf(v1[H][1][r] * mscale, 0.f);
                                *(float4*)&h1[((long)(b0 + imgr) * 6 + oc) * 224 + pyr * 16 + pxb] =
                                    make_float4(a0, a1, a2, a3);
                                vmax = fmaxf(vmax, fmaxf(fmaxf(a0, a1), fmaxf(a2, a3)));
                            }
                        }
                }
            }
        }
    }
    vmax = block_maxN(vmax, red, 8);
    if (tid == 0) amax_slot(slot_out, vmax);
}

// ---------------- conv2 MFMA: padded h1 -> [B,16,25], 4 img/block ----------------
__global__ __launch_bounds__(256) void k_conv2(
    const float* __restrict__ h1, const unsigned short* __restrict__ bf2,
    const unsigned* __restrict__ slots, unsigned* __restrict__ slot_out,
    float* __restrict__ h2)
{
    __shared__ unsigned short xs[4 * IMG2];
    __shared__ float red[4];
    int b0 = blockIdx.x * 4, tid = threadIdx.x;
    int lane = tid & 63, wid = tid >> 6;
    int il = lane & 15, g = lane >> 4;
    short8 Bf[2][8];
    #pragma unroll
    for (int H = 0; H < 2; H++)
        #pragma unroll
        for (int s = 0; s < 8; s++)
            Bf[H][s] = *(const short8*)(bf2 + ((H * 8 + s) * 64 + lane) * 8);
    float s1 = get_scale(slots, 1);
    #pragma unroll
    for (int img = 0; img < 4; img++) {
        const float4* src = (const float4*)(h1 + (long)(b0 + img) * 1344);
        for (int i = tid; i < 336; i += 256) {
            float4 v = src[i];
            unsigned pk0 = f2bf(rintf(v.x / s1)) | (f2bf(rintf(v.y / s1)) << 16);
            unsigned pk1 = f2bf(rintf(v.z / s1)) | (f2bf(rintf(v.w / s1)) << 16);
            *(uint2*)&xs[img * IMG2 + 4 * i] = make_uint2(pk0, pk1);
        }
    }
    __syncthreads();
    float mscale = s1 * get_scale(slots, 6);

    int abase[8];
    #pragma unroll
    for (int s = 0; s < 8; s++) {
        int C = 4 * s + g; if (C > 29) C = 29;
        abase[s] = (il >> 2) * IMG2 + (C / 5) * 224 + (C % 5) * 16;
    }
    int q = il & 3;
    int offq = (q == 0) ? 0 : (6 * q + 1);   // {0,7,13,19}
    int n = il, o = n >> 1;
    bool doStCol = ((n & 1) == 0);
    float vmax = 0.f;
    for (int uu = wid; uu < 7; uu += 4) {
        int p = offq + uu; if (p > 24) p = 24;
        int pb = p / 5, py = p % 5;
        f32x4 acc[2][2];
        #pragma unroll
        for (int H = 0; H < 2; H++)
            #pragma unroll
            for (int yo = 0; yo < 2; yo++) acc[H][yo] = (f32x4){0.f, 0.f, 0.f, 0.f};
        #pragma unroll
        for (int yo = 0; yo < 2; yo++) {
            int y = 2 * py + yo;
            #pragma unroll
            for (int s = 0; s < 8; s++) {
                int addr = abase[s] + y * 16 + 2 * pb;
                union { unsigned u[4]; short8 v; } tA;
                tA.u[0] = *(const unsigned*)(xs + addr);
                tA.u[1] = *(const unsigned*)(xs + addr + 2);
                tA.u[2] = *(const unsigned*)(xs + addr + 4);
                tA.u[3] = *(const unsigned*)(xs + addr + 6);
                acc[0][yo] = __builtin_amdgcn_mfma_f32_16x16x32_bf16(tA.v, Bf[0][s], acc[0][yo], 0, 0, 0);
                acc[1][yo] = __builtin_amdgcn_mfma_f32_16x16x32_bf16(tA.v, Bf[1][s], acc[1][yo], 0, 0, 0);
            }
        }
        #pragma unroll
        for (int H = 0; H < 2; H++)
            #pragma unroll
            for (int r = 0; r < 4; r++) {
                float m = fmaxf(acc[H][0][r], acc[H][1][r]);
                float pooled = fmaxf(m, __shfl_xor(m, 1));
                int cntr = (r == 0) ? 7 : 6;
                if (doStCol && uu < cntr) {
                    int offr = (r == 0) ? 0 : (6 * r + 1);
                    int pr = offr + uu, pbr = pr / 5, pyr = pr % 5;
                    float v = fmaxf(pooled * mscale, 0.f);
                    int oc = 8 * H + o;
                    h2[((long)(b0 + g) * 16 + oc) * 25 + pyr * 5 + pbr] = v;
                    vmax = fmaxf(vmax, v);
                }
            }
    }
    vmax = block_maxN(vmax, red, 4);
    if (tid == 0) amax_slot(slot_out, vmax);
}

// ---------------- conv3 MFMA GEMM: [B,400]x[120,400] -> [B,120], 16 img/block, 8 waves ----------------
__global__ __launch_bounds__(512) void k_conv3(
    const float* __restrict__ h2, const unsigned short* __restrict__ bf3,
    const unsigned* __restrict__ slots, unsigned* __restrict__ slot_out,
    float* __restrict__ h3)
{
    __shared__ unsigned short xs[16 * 408];
    __shared__ float red[8];
    int b0 = blockIdx.x * 16, tid = threadIdx.x;
    int lane = tid & 63, wid = tid >> 6;
    int il = lane & 15, g = lane >> 4;
    short8 Bf[13];
    #pragma unroll
    for (int s = 0; s < 13; s++)
        Bf[s] = *(const short8*)(bf3 + ((wid * 13 + s) * 64 + lane) * 8);
    float s2 = get_scale(slots, 2);
    for (int i = tid; i < 3200; i += 512) {
        int img = i / 200, p = i % 200;
        float2 v = *(const float2*)(h2 + (long)(b0 + img) * 400 + 2 * p);
        unsigned pk = f2bf(rintf(v.x / s2)) | (f2bf(rintf(v.y / s2)) << 16);
        *(unsigned*)&xs[img * 408 + 2 * p] = pk;
    }
    __syncthreads();
    float mscale = s2 * get_scale(slots, 7);
    f32x4 acc = (f32x4){0.f, 0.f, 0.f, 0.f};
    #pragma unroll
    for (int s = 0; s < 13; s++) {
        int C = 4 * s + g; if (C > 49) C = 49;
        int addr = il * 408 + 8 * C;
        union { unsigned long long u[2]; short8 v; } tA;
        tA.u[0] = *(const unsigned long long*)(xs + addr);
        tA.u[1] = *(const unsigned long long*)(xs + addr + 4);
        acc = __builtin_amdgcn_mfma_f32_16x16x32_bf16(tA.v, Bf[s], acc, 0, 0, 0);
    }
    float vmax = 0.f;
    int oc = wid * 16 + il;
    if (oc < 120) {
        #pragma unroll
        for (int r = 0; r < 4; r++) {
            float v = fmaxf(acc[r] * mscale, 0.f);
            h3[(long)(b0 + 4 * g + r) * 120 + oc] = v;
            vmax = fmaxf(vmax, v);
        }
    }
    vmax = block_maxN(vmax, red, 8);
    if (tid == 0) amax_slot(slot_out, vmax);
}

// ---------------- fc4 MFMA GEMM: [B,120]x[84,120] -> [B,84], 16 img/block, 8 waves ----------------
__global__ __launch_bounds__(512) void k_fc4(
    const float* __restrict__ h3, const unsigned short* __restrict__ bf4,
    const unsigned* __restrict__ slots, unsigned* __restrict__ slot_out,
    float* __restrict__ h4)
{
    __shared__ unsigned short xs[16 * 136];
    __shared__ float red[8];
    int b0 = blockIdx.x * 16, tid = threadIdx.x;
    int lane = tid & 63, wid = tid >> 6;
    int il = lane & 15, g = lane >> 4;
    short8 Bf[4];
    if (wid < 6) {
        #pragma unroll
        for (int s = 0; s < 4; s++)
            Bf[s] = *(const short8*)(bf4 + ((wid * 4 + s) * 64 + lane) * 8);
    }
    float s3 = get_scale(slots, 3);
    for (int i = tid; i < 960; i += 512) {
        int img = i / 60, p = i % 60;
        float2 v = *(const float2*)(h3 + (long)(b0 + img) * 120 + 2 * p);
        unsigned pk = f2bf(rintf(v.x / s3)) | (f2bf(rintf(v.y / s3)) << 16);
        *(unsigned*)&xs[img * 136 + 2 * p] = pk;
    }
    __syncthreads();
    float mscale = s3 * get_scale(slots, 8);
    float vmax = 0.f;
    if (wid < 6) {
        f32x4 acc = (f32x4){0.f, 0.f, 0.f, 0.f};
        #pragma unroll
        for (int s = 0; s < 4; s++) {
            int C = 4 * s + g; if (C > 14) C = 14;
            int addr = il * 136 + 8 * C;
            union { unsigned long long u[2]; short8 v; } tA;
            tA.u[0] = *(const unsigned long long*)(xs + addr);
            tA.u[1] = *(const unsigned long long*)(xs + addr + 4);
            acc = __builtin_amdgcn_mfma_f32_16x16x32_bf16(tA.v, Bf[s], acc, 0, 0, 0);
        }
        int oc = wid * 16 + il;
        if (oc < 84) {
            #pragma unroll
            for (int r = 0; r < 4; r++) {
                float v = fmaxf(acc[r] * mscale, 0.f);
                h4[(long)(b0 + 4 * g + r) * 84 + oc] = v;
                vmax = fmaxf(vmax, v);
            }
        }
    }
    vmax = block_maxN(vmax, red, 8);
    if (tid == 0) amax_slot(slot_out, vmax);
}

// ---------------- fc5 MFMA: [B,84]x[10,84] -> out [B,10]; 4 indep waves x 16 img ----------------
__global__ __launch_bounds__(256) void k_fc5(
    const float* __restrict__ h4, const unsigned short* __restrict__ bf5,
    const unsigned* __restrict__ slots, float* __restrict__ out)
{
    __shared__ unsigned short xs[4 * 16 * 104];
    int tid = threadIdx.x;
    int lane = tid & 63, w = tid >> 6;
    int il = lane & 15, g = lane >> 4;
    int b0w = blockIdx.x * 64 + w * 16;
    short8 Bf[3];
    #pragma unroll
    for (int s = 0; s < 3; s++)
        Bf[s] = *(const short8*)(bf5 + ((s * 64) + lane) * 8);
    float s4 = get_scale(slots, 4);
    for (int i = lane; i < 672; i += 64) {
        int img = i / 42, j = i % 42;
        float2 v = *(const float2*)(h4 + (long)(b0w + img) * 84 + 2 * j);
        unsigned pk = f2bf(rintf(v.x / s4)) | (f2bf(rintf(v.y / s4)) << 16);
        *(unsigned*)&xs[w * 1664 + img * 104 + 2 * j] = pk;
    }
    for (int i = lane; i < 96; i += 64) {   // zero pad k=84..95
        int img = i / 6, j = i % 6;
        *(unsigned*)&xs[w * 1664 + img * 104 + 84 + 2 * j] = 0u;
    }
    __syncthreads();
    float mscale = s4 * get_scale(slots, 9);
    f32x4 acc = (f32x4){0.f, 0.f, 0.f, 0.f};
    #pragma unroll
    for (int s = 0; s < 3; s++) {
        int addr = w * 1664 + il * 104 + 32 * s + 8 * g;
        union { unsigned long long u[2]; short8 v; } tA;
        tA.u[0] = *(const unsigned long long*)(xs + addr);
        tA.u[1] = *(const unsigned long long*)(xs + addr + 4);
        acc = __builtin_amdgcn_mfma_f32_16x16x32_bf16(tA.v, Bf[s], acc, 0, 0, 0);
    }
    if (il < 10) {
        #pragma unroll
        for (int r = 0; r < 4; r++)
            out[(long)(b0w + 4 * g + r) * 10 + il] = acc[r] * mscale;
    }
}

extern "C" void kernel_launch(void* const* d_in, const int* in_sizes, int n_in,
                              void* d_out, int out_size, void* d_ws, size_t ws_size,
                              hipStream_t stream) {
    const float* x  = (const float*)d_in[0];
    const float* w1 = (const float*)d_in[1];
    const float* w2 = (const float*)d_in[2];
    const float* w3 = (const float*)d_in[3];
    const float* w4 = (const float*)d_in[4];
    const float* w5 = (const float*)d_in[5];
    float* out = (float*)d_out;
    float* ws = (float*)d_ws;
    unsigned* slots = (unsigned*)d_ws;
    unsigned short* bf1 = (unsigned short*)(ws + OFF_BF1);
    unsigned short* bf2 = (unsigned short*)(ws + OFF_BF2);
    unsigned short* bf3 = (unsigned short*)(ws + OFF_BF3);
    unsigned short* bf4 = (unsigned short*)(ws + OFF_BF4);
    unsigned short* bf5 = (unsigned short*)(ws + OFF_BF5);
    float* h1 = ws + OFF_H1;
    float* h2 = ws + OFF_H2;
    float* h3 = ws + OFF_H3;   // reuses h1's region (dead after conv2)
    float* h4 = ws + OFF_H4;

    k_absmax_all<<<2112, 256, 0, stream>>>((const float4*)x, w1, w2, w3, w4, w5, slots);
    k_bfrag<<<310, 256, 0, stream>>>(w1, w2, w3, w4, w5, slots, bf1, bf2, bf3, bf4, bf5);
    k_conv1<<<683, 512, 0, stream>>>(x, bf1, slots, slots + 1, h1);
    k_conv2<<<1024, 256, 0, stream>>>(h1, bf2, slots, slots + 2, h2);
    k_conv3<<<256, 512, 0, stream>>>(h2, bf3, slots, slots + 3, h3);
    k_fc4<<<256, 512, 0, stream>>>(h3, bf4, slots, slots + 4, h4);
    k_fc5<<<64, 256, 0, stream>>>(h4, bf5, slots, out);
}

// Round 18
// 103.853 us; speedup vs baseline: 1.1236x; 1.1236x over previous
//
#include <hip/hip_runtime.h>
#include <hip/hip_bf16.h>

#define QMAX 255.0f

typedef __attribute__((ext_vector_type(8))) short short8;
typedef __attribute__((ext_vector_type(4))) float f32x4;

// ws float offsets
#define OFF_BF1   16       // ushort[4096]
#define OFF_BF2   2064     // ushort[8192]
#define OFF_BF3   6160     // ushort[53248]
#define OFF_BF4   32784    // ushort[12288]
#define OFF_BF5   38928    // ushort[1536]
#define OFF_H1    40960    // padded f32 [4096][6][14][16]
#define OFF_H2    5545984  // f32 [4096][400]  (28.7 MB high water)
#define OFF_H3    40960    // reuses dead h1 region: f32 [4096][120]
#define OFF_H4    532480   // f32 [4096][84]

#define IMG1 3080   // shorts/img conv1 LDS (1540 dw)
#define IMG2 1352   // shorts/img conv2 LDS (676 dw)

__device__ __forceinline__ float get_scale(const unsigned* slots, int i) {
    float amax = __uint_as_float(slots[i]);
    float s = amax / QMAX;
    if (!(s > 0.0f)) s = 1.0f;
    return s;
}
__device__ __forceinline__ unsigned f2bf(float f) { return __float_as_uint(f) >> 16; } // exact for our ints

// signed atomicMax on float bits: valid for non-negative floats; 0xAA poison is
// negative as int -> no slot zeroing needed, and replays are idempotent.
__device__ __forceinline__ void amax_slot(unsigned* p, float v) {
    atomicMax((int*)p, (int)__float_as_uint(v));
}

__device__ __forceinline__ float block_maxN(float v, float* red, int nw) {
    #pragma unroll
    for (int off = 32; off > 0; off >>= 1) v = fmaxf(v, __shfl_xor(v, off));
    if ((threadIdx.x & 63) == 0) red[threadIdx.x >> 6] = v;
    __syncthreads();
    float m = red[0];
    for (int i = 1; i < nw; i++) m = fmaxf(m, red[i]);
    return m;
}

// ---------------- absmax: x (blocks 0..2047) + all 5 weights (parallel w3/w4 scans) ----------------
__global__ __launch_bounds__(256) void k_absmax_all(
    const float4* __restrict__ x4,
    const float* __restrict__ w1, const float* __restrict__ w2,
    const float* __restrict__ w3, const float* __restrict__ w4,
    const float* __restrict__ w5, unsigned* __restrict__ slots)
{
    __shared__ float red[4];
    int b = blockIdx.x, tid = threadIdx.x;
    float m = 0.0f;
    int slot = -1;
    if (b < 2048) {
        slot = 0;
        for (int i = b * 256 + tid; i < 3145728; i += 2048 * 256) {
            float4 v = x4[i];
            m = fmaxf(m, fmaxf(fmaxf(fabsf(v.x), fabsf(v.y)), fmaxf(fabsf(v.z), fabsf(v.w))));
        }
    } else {
        int b2 = b - 2048;
        const float* w = nullptr; int n = 0, start = 0, stride = 256;
        if (b2 < 48)      { w = w3; n = 48000; start = b2 * 256;        stride = 48 * 256; slot = 7; }
        else if (b2 < 58) { w = w4; n = 10080; start = (b2 - 48) * 256; stride = 10 * 256; slot = 8; }
        else if (b2 == 58){ w = w2; n = 2400;  slot = 6; }
        else if (b2 == 59){ w = w1; n = 450;   slot = 5; }
        else if (b2 == 60){ w = w5; n = 840;   slot = 9; }
        if (slot >= 0)
            for (int i = start + tid; i < n; i += stride) m = fmaxf(m, fabsf(w[i]));
    }
    m = block_maxN(m, red, 4);
    if (tid == 0 && slot >= 0) amax_slot(&slots[slot], m);
}

// ---------------- build MFMA B-fragments ----------------
__global__ __launch_bounds__(256) void k_bfrag(
    const float* __restrict__ w1, const float* __restrict__ w2,
    const float* __restrict__ w3, const float* __restrict__ w4,
    const float* __restrict__ w5, const unsigned* __restrict__ slots,
    unsigned short* __restrict__ bf1, unsigned short* __restrict__ bf2,
    unsigned short* __restrict__ bf3, unsigned short* __restrict__ bf4,
    unsigned short* __restrict__ bf5)
{
    int idx = blockIdx.x * 256 + threadIdx.x;
    if (idx < 4096) {                     // conv1: [H2][S4][64][8], n=o*4+dx (o<3,dx<4)
        int f = idx, e = f & 7, l = (f >> 3) & 63, s = (f >> 9) & 3, H = f >> 11;
        int n = l & 15, g = l >> 4, C = 4 * s + g;
        float v = 0.f;
        if (n < 12 && C < 15) {
            int o = n >> 2, dx = n & 3, kx = e - dx;
            if (kx >= 0 && kx <= 4) {
                int c = C / 5, ky = C % 5, oc = 3 * H + o;
                v = rintf(w1[((oc * 3 + c) * 5 + ky) * 5 + kx] / get_scale(slots, 5));
            }
        }
        bf1[f] = (unsigned short)f2bf(v);
    } else if (idx < 12288) {             // conv2: [H2][S8][64][8], n=o*2+dx (o<8,dx<2)
        int f = idx - 4096, e = f & 7, l = (f >> 3) & 63, s = (f >> 9) & 7, H = f >> 12;
        int n = l & 15, g = l >> 4, C = 4 * s + g;
        float v = 0.f;
        if (C < 30) {
            int o = n >> 1, dx = n & 1, kx = e - dx;
            if (kx >= 0 && kx <= 4) {
                int c = C / 5, ky = C % 5, oc = 8 * H + o;
                v = rintf(w2[((oc * 6 + c) * 5 + ky) * 5 + kx] / get_scale(slots, 6));
            }
        }
        bf2[f] = (unsigned short)f2bf(v);
    } else if (idx < 65536) {             // conv3: [Nt8][S13][64][8]
        int f = idx - 12288, e = f & 7, l = (f >> 3) & 63, r = f >> 9;
        int s = r % 13, Nt = r / 13;
        int oc = Nt * 16 + (l & 15), k = 32 * s + 8 * (l >> 4) + e;
        float v = 0.f;
        if (oc < 120 && k < 400) v = rintf(w3[oc * 400 + k] / get_scale(slots, 7));
        bf3[f] = (unsigned short)f2bf(v);
    } else if (idx < 77824) {             // fc4: [Nt6][S4][64][8]
        int f = idx - 65536, e = f & 7, l = (f >> 3) & 63, r = f >> 9;
        int s = r & 3, Nt = r >> 2;
        int oc = Nt * 16 + (l & 15), k = 32 * s + 8 * (l >> 4) + e;
        float v = 0.f;
        if (oc < 84 && k < 120) v = rintf(w4[oc * 120 + k] / get_scale(slots, 8));
        bf4[f] = (unsigned short)f2bf(v);
    } else if (idx < 79360) {             // fc5: [S3][64][8]
        int f = idx - 77824, e = f & 7, l = (f >> 3) & 63, s = f >> 9;
        int oc = l & 15, k = 32 * s + 8 * (l >> 4) + e;
        float v = 0.f;
        if (oc < 10 && k < 84) v = rintf(w5[oc * 84 + k] / get_scale(slots, 9));
        bf5[f] = (unsigned short)f2bf(v);
    }
}

// ---------------- conv1 MFMA: [B,3,32,32] -> padded h1 [B,6,14,16], 8 img/block ----------------
// A-row il = 2*img + half; half selects py in {0..6} / {7..13}; wave = uu = py-in-half;
// pb = inner register loop -> full-row float4 stores (no partial-line RMW).
__global__ __launch_bounds__(512) void k_conv1(
    const float* __restrict__ x, const unsigned short* __restrict__ bf1,
    const unsigned* __restrict__ slots, unsigned* __restrict__ slot_out,
    float* __restrict__ h1)
{
    __shared__ unsigned short xs[8 * IMG1];
    __shared__ float red[8];
    int b0 = blockIdx.x * 8, tid = threadIdx.x;
    int lane = tid & 63, wid = tid >> 6;
    int il = lane & 15, g = lane >> 4;
    short8 Bf[2][4];
    #pragma unroll
    for (int H = 0; H < 2; H++)
        #pragma unroll
        for (int s = 0; s < 4; s++)
            Bf[H][s] = *(const short8*)(bf1 + ((H * 4 + s) * 64 + lane) * 8);
    float sx = get_scale(slots, 0);
    #pragma unroll
    for (int img = 0; img < 8; img++) {
        const float* xb = x + (long)(b0 + img) * 3072;
        for (int i = tid; i < 768; i += 512) {           // quad-index float4 staging
            int c = i >> 8, rem = i & 255, yy = rem >> 3, c4 = (rem & 7) << 2;
            float4 v = *(const float4*)(xb + c * 1024 + yy * 32 + c4);
            uint2 pk;
            pk.x = f2bf(rintf(v.x / sx)) | (f2bf(rintf(v.y / sx)) << 16);
            pk.y = f2bf(rintf(v.z / sx)) | (f2bf(rintf(v.w / sx)) << 16);
            *(uint2*)&xs[img * IMG1 + c * 1024 + yy * 32 + c4] = pk;
        }
    }
    __syncthreads();
    float mscale = sx * get_scale(slots, 5);

    int abase[4];
    #pragma unroll
    for (int s = 0; s < 4; s++) {
        int C = 4 * s + g; if (C > 14) C = 14;
        abase[s] = (il >> 1) * IMG1 + (C / 5) * 1024 + (C % 5) * 32 + (il & 1) * 448;
    }
    int o = il >> 2;
    bool doSt = ((il & 3) == 0) && (il < 12);
    float vmax = 0.f;
    if (wid < 7) {
        int uu = wid;                 // py within half (0..6)
        int ybase = uu * 64;          // (2*uu)*32 shorts
        f32x4 v0[2][2], v1[2][2];     // [H][pb&1] pooled px-pairs
        #pragma unroll
        for (int pb = 0; pb < 7; pb++) {
            f32x4 acc[2][2];
            #pragma unroll
            for (int H = 0; H < 2; H++)
                #pragma unroll
                for (int yo = 0; yo < 2; yo++) acc[H][yo] = (f32x4){0.f, 0.f, 0.f, 0.f};
            #pragma unroll
            for (int yo = 0; yo < 2; yo++) {
                #pragma unroll
                for (int s = 0; s < 4; s++) {
                    int addr = abase[s] + ybase + yo * 32 + 4 * pb;
                    union { unsigned long long u[2]; short8 v; } tA;
                    tA.u[0] = *(const unsigned long long*)(xs + addr);
                    tA.u[1] = *(const unsigned long long*)(xs + addr + 4);
                    acc[0][yo] = __builtin_amdgcn_mfma_f32_16x16x32_bf16(tA.v, Bf[0][s], acc[0][yo], 0, 0, 0);
                    acc[1][yo] = __builtin_amdgcn_mfma_f32_16x16x32_bf16(tA.v, Bf[1][s], acc[1][yo], 0, 0, 0);
                }
            }
            #pragma unroll
            for (int H = 0; H < 2; H++) {
                #pragma unroll
                for (int r = 0; r < 4; r++) {
                    float ym = fmaxf(acc[H][0][r], acc[H][1][r]);     // pool y-pair
                    float p  = fmaxf(ym, __shfl_xor(ym, 1));          // pool dx-pair
                    v0[H][pb & 1][r] = p;
                    v1[H][pb & 1][r] = __shfl_xor(p, 2);              // partner px
                }
            }
            if ((pb & 1) || pb == 6) {                                // flush 2-pb batch
                int pxb = (pb == 6) ? 12 : 2 * (pb - 1);
                bool last = (pb == 6);
                if (doSt) {
                    #pragma unroll
                    for (int H = 0; H < 2; H++)
                        #pragma unroll
                        for (int r = 0; r < 4; r++) {
                            int imgr = 2 * g + (r >> 1);
                            int pyr = 7 * (r & 1) + uu;
                            int oc = 3 * H + o;
                            float a0 = fmaxf(v0[H][0][r] * mscale, 0.f);
                            float a1 = fmaxf(v1[H][0][r] * mscale, 0.f);
                            float a2 = last ? 0.f : fmaxf(v0[H][1][r] * mscale, 0.f);
                            float a3 = last ? 0.f : fmaxf(v1[H][1][r] * mscale, 0.f);
                            *(float4*)&h1[((long)(b0 + imgr) * 6 + oc) * 224 + pyr * 16 + pxb] =
                                make_float4(a0, a1, a2, a3);
                            vmax = fmaxf(vmax, fmaxf(fmaxf(a0, a1), fmaxf(a2, a3)));
                        }
                }
            }
        }
    }
    vmax = block_maxN(vmax, red, 8);
    if (tid == 0) amax_slot(slot_out, vmax);
}

// ---------------- conv2 MFMA: padded h1 -> [B,16,25], 4 img/block ----------------
__global__ __launch_bounds__(256) void k_conv2(
    const float* __restrict__ h1, const unsigned short* __restrict__ bf2,
    const unsigned* __restrict__ slots, unsigned* __restrict__ slot_out,
    float* __restrict__ h2)
{
    __shared__ unsigned short xs[4 * IMG2];
    __shared__ float red[4];
    int b0 = blockIdx.x * 4, tid = threadIdx.x;
    int lane = tid & 63, wid = tid >> 6;
    int il = lane & 15, g = lane >> 4;
    short8 Bf[2][8];
    #pragma unroll
    for (int H = 0; H < 2; H++)
        #pragma unroll
        for (int s = 0; s < 8; s++)
            Bf[H][s] = *(const short8*)(bf2 + ((H * 8 + s) * 64 + lane) * 8);
    float s1 = get_scale(slots, 1);
    #pragma unroll
    for (int img = 0; img < 4; img++) {
        const float4* src = (const float4*)(h1 + (long)(b0 + img) * 1344);
        for (int i = tid; i < 336; i += 256) {
            float4 v = src[i];
            unsigned pk0 = f2bf(rintf(v.x / s1)) | (f2bf(rintf(v.y / s1)) << 16);
            unsigned pk1 = f2bf(rintf(v.z / s1)) | (f2bf(rintf(v.w / s1)) << 16);
            *(uint2*)&xs[img * IMG2 + 4 * i] = make_uint2(pk0, pk1);
        }
    }
    __syncthreads();
    float mscale = s1 * get_scale(slots, 6);

    int abase[8];
    #pragma unroll
    for (int s = 0; s < 8; s++) {
        int C = 4 * s + g; if (C > 29) C = 29;
        abase[s] = (il >> 2) * IMG2 + (C / 5) * 224 + (C % 5) * 16;
    }
    int q = il & 3;
    int offq = (q == 0) ? 0 : (6 * q + 1);   // {0,7,13,19}
    int n = il, o = n >> 1;
    bool doStCol = ((n & 1) == 0);
    float vmax = 0.f;
    for (int uu = wid; uu < 7; uu += 4) {
        int p = offq + uu; if (p > 24) p = 24;
        int pb = p / 5, py = p % 5;
        f32x4 acc[2][2];
        #pragma unroll
        for (int H = 0; H < 2; H++)
            #pragma unroll
            for (int yo = 0; yo < 2; yo++) acc[H][yo] = (f32x4){0.f, 0.f, 0.f, 0.f};
        #pragma unroll
        for (int yo = 0; yo < 2; yo++) {
            int y = 2 * py + yo;
            #pragma unroll
            for (int s = 0; s < 8; s++) {
                int addr = abase[s] + y * 16 + 2 * pb;
                union { unsigned u[4]; short8 v; } tA;
                tA.u[0] = *(const unsigned*)(xs + addr);
                tA.u[1] = *(const unsigned*)(xs + addr + 2);
                tA.u[2] = *(const unsigned*)(xs + addr + 4);
                tA.u[3] = *(const unsigned*)(xs + addr + 6);
                acc[0][yo] = __builtin_amdgcn_mfma_f32_16x16x32_bf16(tA.v, Bf[0][s], acc[0][yo], 0, 0, 0);
                acc[1][yo] = __builtin_amdgcn_mfma_f32_16x16x32_bf16(tA.v, Bf[1][s], acc[1][yo], 0, 0, 0);
            }
        }
        #pragma unroll
        for (int H = 0; H < 2; H++)
            #pragma unroll
            for (int r = 0; r < 4; r++) {
                float m = fmaxf(acc[H][0][r], acc[H][1][r]);
                float pooled = fmaxf(m, __shfl_xor(m, 1));
                int cntr = (r == 0) ? 7 : 6;
                if (doStCol && uu < cntr) {
                    int offr = (r == 0) ? 0 : (6 * r + 1);
                    int pr = offr + uu, pbr = pr / 5, pyr = pr % 5;
                    float v = fmaxf(pooled * mscale, 0.f);
                    int oc = 8 * H + o;
                    h2[((long)(b0 + g) * 16 + oc) * 25 + pyr * 5 + pbr] = v;
                    vmax = fmaxf(vmax, v);
                }
            }
    }
    vmax = block_maxN(vmax, red, 4);
    if (tid == 0) amax_slot(slot_out, vmax);
}

// ---------------- conv3 MFMA GEMM: [B,400]x[120,400] -> [B,120], 16 img/block, 8 waves ----------------
__global__ __launch_bounds__(512) void k_conv3(
    const float* __restrict__ h2, const unsigned short* __restrict__ bf3,
    const unsigned* __restrict__ slots, unsigned* __restrict__ slot_out,
    float* __restrict__ h3)
{
    __shared__ unsigned short xs[16 * 408];
    __shared__ float red[8];
    int b0 = blockIdx.x * 16, tid = threadIdx.x;
    int lane = tid & 63, wid = tid >> 6;
    int il = lane & 15, g = lane >> 4;
    short8 Bf[13];
    #pragma unroll
    for (int s = 0; s < 13; s++)
        Bf[s] = *(const short8*)(bf3 + ((wid * 13 + s) * 64 + lane) * 8);
    float s2 = get_scale(slots, 2);
    for (int i = tid; i < 3200; i += 512) {
        int img = i / 200, p = i % 200;
        float2 v = *(const float2*)(h2 + (long)(b0 + img) * 400 + 2 * p);
        unsigned pk = f2bf(rintf(v.x / s2)) | (f2bf(rintf(v.y / s2)) << 16);
        *(unsigned*)&xs[img * 408 + 2 * p] = pk;
    }
    __syncthreads();
    float mscale = s2 * get_scale(slots, 7);
    f32x4 acc = (f32x4){0.f, 0.f, 0.f, 0.f};
    #pragma unroll
    for (int s = 0; s < 13; s++) {
        int C = 4 * s + g; if (C > 49) C = 49;
        int addr = il * 408 + 8 * C;
        union { unsigned long long u[2]; short8 v; } tA;
        tA.u[0] = *(const unsigned long long*)(xs + addr);
        tA.u[1] = *(const unsigned long long*)(xs + addr + 4);
        acc = __builtin_amdgcn_mfma_f32_16x16x32_bf16(tA.v, Bf[s], acc, 0, 0, 0);
    }
    float vmax = 0.f;
    int oc = wid * 16 + il;
    if (oc < 120) {
        #pragma unroll
        for (int r = 0; r < 4; r++) {
            float v = fmaxf(acc[r] * mscale, 0.f);
            h3[(long)(b0 + 4 * g + r) * 120 + oc] = v;
            vmax = fmaxf(vmax, v);
        }
    }
    vmax = block_maxN(vmax, red, 8);
    if (tid == 0) amax_slot(slot_out, vmax);
}

// ---------------- fc4 MFMA GEMM: [B,120]x[84,120] -> [B,84], 16 img/block, 8 waves ----------------
__global__ __launch_bounds__(512) void k_fc4(
    const float* __restrict__ h3, const unsigned short* __restrict__ bf4,
    const unsigned* __restrict__ slots, unsigned* __restrict__ slot_out,
    float* __restrict__ h4)
{
    __shared__ unsigned short xs[16 * 136];
    __shared__ float red[8];
    int b0 = blockIdx.x * 16, tid = threadIdx.x;
    int lane = tid & 63, wid = tid >> 6;
    int il = lane & 15, g = lane >> 4;
    short8 Bf[4];
    if (wid < 6) {
        #pragma unroll
        for (int s = 0; s < 4; s++)
            Bf[s] = *(const short8*)(bf4 + ((wid * 4 + s) * 64 + lane) * 8);
    }
    float s3 = get_scale(slots, 3);
    for (int i = tid; i < 960; i += 512) {
        int img = i / 60, p = i % 60;
        float2 v = *(const float2*)(h3 + (long)(b0 + img) * 120 + 2 * p);
        unsigned pk = f2bf(rintf(v.x / s3)) | (f2bf(rintf(v.y / s3)) << 16);
        *(unsigned*)&xs[img * 136 + 2 * p] = pk;
    }
    __syncthreads();
    float mscale = s3 * get_scale(slots, 8);
    float vmax = 0.f;
    if (wid < 6) {
        f32x4 acc = (f32x4){0.f, 0.f, 0.f, 0.f};
        #pragma unroll
        for (int s = 0; s < 4; s++) {
            int C = 4 * s + g; if (C > 14) C = 14;
            int addr = il * 136 + 8 * C;
            union { unsigned long long u[2]; short8 v; } tA;
            tA.u[0] = *(const unsigned long long*)(xs + addr);
            tA.u[1] = *(const unsigned long long*)(xs + addr + 4);
            acc = __builtin_amdgcn_mfma_f32_16x16x32_bf16(tA.v, Bf[s], acc, 0, 0, 0);
        }
        int oc = wid * 16 + il;
        if (oc < 84) {
            #pragma unroll
            for (int r = 0; r < 4; r++) {
                float v = fmaxf(acc[r] * mscale, 0.f);
                h4[(long)(b0 + 4 * g + r) * 84 + oc] = v;
                vmax = fmaxf(vmax, v);
            }
        }
    }
    vmax = block_maxN(vmax, red, 8);
    if (tid == 0) amax_slot(slot_out, vmax);
}

// ---------------- fc5 MFMA: [B,84]x[10,84] -> out [B,10]; 4 indep waves x 16 img ----------------
__global__ __launch_bounds__(256) void k_fc5(
    const float* __restrict__ h4, const unsigned short* __restrict__ bf5,
    const unsigned* __restrict__ slots, float* __restrict__ out)
{
    __shared__ unsigned short xs[4 * 16 * 104];
    int tid = threadIdx.x;
    int lane = tid & 63, w = tid >> 6;
    int il = lane & 15, g = lane >> 4;
    int b0w = blockIdx.x * 64 + w * 16;
    short8 Bf[3];
    #pragma unroll
    for (int s = 0; s < 3; s++)
        Bf[s] = *(const short8*)(bf5 + ((s * 64) + lane) * 8);
    float s4 = get_scale(slots, 4);
    for (int i = lane; i < 672; i += 64) {
        int img = i / 42, j = i % 42;
        float2 v = *(const float2*)(h4 + (long)(b0w + img) * 84 + 2 * j);
        unsigned pk = f2bf(rintf(v.x / s4)) | (f2bf(rintf(v.y / s4)) << 16);
        *(unsigned*)&xs[w * 1664 + img * 104 + 2 * j] = pk;
    }
    for (int i = lane; i < 96; i += 64) {   // zero pad k=84..95
        int img = i / 6, j = i % 6;
        *(unsigned*)&xs[w * 1664 + img * 104 + 84 + 2 * j] = 0u;
    }
    __syncthreads();
    float mscale = s4 * get_scale(slots, 9);
    f32x4 acc = (f32x4){0.f, 0.f, 0.f, 0.f};
    #pragma unroll
    for (int s = 0; s < 3; s++) {
        int addr = w * 1664 + il * 104 + 32 * s + 8 * g;
        union { unsigned long long u[2]; short8 v; } tA;
        tA.u[0] = *(const unsigned long long*)(xs + addr);
        tA.u[1] = *(const unsigned long long*)(xs + addr + 4);
        acc = __builtin_amdgcn_mfma_f32_16x16x32_bf16(tA.v, Bf[s], acc, 0, 0, 0);
    }
    if (il < 10) {
        #pragma unroll
        for (int r = 0; r < 4; r++)
            out[(long)(b0w + 4 * g + r) * 10 + il] = acc[r] * mscale;
    }
}

extern "C" void kernel_launch(void* const* d_in, const int* in_sizes, int n_in,
                              void* d_out, int out_size, void* d_ws, size_t ws_size,
                              hipStream_t stream) {
    const float* x  = (const float*)d_in[0];
    const float* w1 = (const float*)d_in[1];
    const float* w2 = (const float*)d_in[2];
    const float* w3 = (const float*)d_in[3];
    const float* w4 = (const float*)d_in[4];
    const float* w5 = (const float*)d_in[5];
    float* out = (float*)d_out;
    float* ws = (float*)d_ws;
    unsigned* slots = (unsigned*)d_ws;
    unsigned short* bf1 = (unsigned short*)(ws + OFF_BF1);
    unsigned short* bf2 = (unsigned short*)(ws + OFF_BF2);
    unsigned short* bf3 = (unsigned short*)(ws + OFF_BF3);
    unsigned short* bf4 = (unsigned short*)(ws + OFF_BF4);
    unsigned short* bf5 = (unsigned short*)(ws + OFF_BF5);
    float* h1 = ws + OFF_H1;
    float* h2 = ws + OFF_H2;
    float* h3 = ws + OFF_H3;   // reuses h1's region (dead after conv2)
    float* h4 = ws + OFF_H4;

    k_absmax_all<<<2112, 256, 0, stream>>>((const float4*)x, w1, w2, w3, w4, w5, slots);
    k_bfrag<<<310, 256, 0, stream>>>(w1, w2, w3, w4, w5, slots, bf1, bf2, bf3, bf4, bf5);
    k_conv1<<<512, 512, 0, stream>>>(x, bf1, slots, slots + 1, h1);
    k_conv2<<<1024, 256, 0, stream>>>(h1, bf2, slots, slots + 2, h2);
    k_conv3<<<256, 512, 0, stream>>>(h2, bf3, slots, slots + 3, h3);
    k_fc4<<<256, 512, 0, stream>>>(h3, bf4, slots, slots + 4, h4);
    k_fc5<<<64, 256, 0, stream>>>(h4, bf5, slots, out);
}